// Round 2
// baseline (92.596 us; speedup 1.0000x reference)
//
#include <hip/hip_runtime.h>
#include <hip/hip_fp16.h>

// x: (2,8,256,256) fp32, F: 3x3 fp32.
#define HS 256
#define WSZ 256
#define NPIX (HS * WSZ)        // 65536 pixels
#define NCH 16                 // B*C
#define NELEM (NPIX * NCH)     // half elements in T

typedef float f4 __attribute__((ext_vector_type(4)));

// ---------------------------------------------------------------------------
// Transpose + fp16 quantize: (bc, h, w) f32 -> (h, w, bc) f16, LDS-tiled,
// coalesced both sides. Geometry/rint decisions are unaffected (they use F
// in fp32); only sampled VALUES are RTN-quantized once here.
// Also zeroes a 512 B pad at T[NELEM..) — the invalid-sample redirect target.
// ---------------------------------------------------------------------------
__global__ __launch_bounds__(256) void transpose_f16(const float* __restrict__ x,
                                                     __half* __restrict__ T) {
    __shared__ float lds[16][257];   // +1 pad
    int tid  = threadIdx.x;
    int base = blockIdx.x * 256;
#pragma unroll
    for (int ch = 0; ch < 16; ++ch)
        lds[ch][tid] = x[ch * NPIX + base + tid];   // coalesced 1KB per instr
    if (blockIdx.x == 0 && tid < 128)
        ((unsigned int*)(T + NELEM))[tid] = 0u;     // 512 B zero pad
    __syncthreads();
    uint2* T2 = (uint2*)T;           // 8 B = 4 halves = one channel-quad
#pragma unroll
    for (int it = 0; it < 4; ++it) {
        int idx = it * 256 + tid;    // 0..1023 uint2 of this tile
        int p   = idx >> 2;          // local pixel
        int q   = idx & 3;           // channel quad
        __half2 a = __floats2half2_rn(lds[q * 4 + 0][p], lds[q * 4 + 1][p]);
        __half2 b = __floats2half2_rn(lds[q * 4 + 2][p], lds[q * 4 + 3][p]);
        uint2 o;
        o.x = __builtin_bit_cast(unsigned int, a);
        o.y = __builtin_bit_cast(unsigned int, b);
        T2[base * 4 + idx] = o;      // contiguous 8B/lane -> coalesced
    }
}

// ---------------------------------------------------------------------------
// Geometry (bit-exact, verified R6): FMA-contracted einsum, f32. UNCHANGED.
// ---------------------------------------------------------------------------
struct LineGeom {
    float p, q, c;
    bool  col;
};

__device__ __forceinline__ LineGeom make_geom(const float* __restrict__ F, int pix) {
#pragma clang fp contract(off)
    int w = pix & (WSZ - 1);
    int h = pix >> 8;
    float u = (float)w, v = (float)h;
    float a = __builtin_fmaf(F[3], v, F[0] * u) + F[6];
    float b = __builtin_fmaf(F[4], v, F[1] * u) + F[7];
    float c = __builtin_fmaf(F[5], v, F[2] * u) + F[8];
    const float eps = 1e-8f;
    float bs = (fabsf(b) < eps) ? eps : b;
    float as = (fabsf(a) < eps) ? eps : a;
    LineGeom g;
    g.col = (fabsf(b) >= fabsf(a));
    g.p   = g.col ? a : b;
    g.q   = g.col ? bs : as;
    g.c   = c;
    return g;
}

// Chain (bit-exact, verified R6): t = fma(p,s,c); y = (-t)/q IEEE f32; rint.
// MUST stay a true IEEE divide per sample: rcp-based y flips rint at half-
// integer boundaries (~1e2 samples over the grid) and blows the tolerance.
__device__ __forceinline__ int chainY(const LineGeom& g, int s) {
#pragma clang fp contract(off)
    float t  = __builtin_fmaf(g.p, (float)s, g.c);
    float y  = (-t) / g.q;
    return (int)__builtin_rintf(y);
}

// fp16 x8 (one 16B lane-load = 8 channels) -> two f32x4 accumulators
__device__ __forceinline__ void acc16(uint4 v, f4& a0, f4& a1) {
    float2 p0 = __half22float2(__builtin_bit_cast(__half2, v.x));
    float2 p1 = __half22float2(__builtin_bit_cast(__half2, v.y));
    float2 p2 = __half22float2(__builtin_bit_cast(__half2, v.z));
    float2 p3 = __half22float2(__builtin_bit_cast(__half2, v.w));
    f4 u0 = {p0.x, p0.y, p1.x, p1.y};
    f4 u1 = {p2.x, p2.y, p3.x, p3.y};
    a0 += u0;
    a1 += u1;
}

// ---------------------------------------------------------------------------
// Gather v3: 16 lanes/pixel = 8 sample-slots x 2 channel-halves.
// Lane r (=2k+h) loads 16 B (8 channels, half h) of sample s = 8m+k each
// round m; the pixel's 16 lanes thus cover 8 CONSECUTIVE samples = 256 B
// contiguous per load instruction (epipole at (828,128) -> |dy/ds| <= 0.22,
// so the 8-run is 2-3 cache lines, vs 16 scattered lines in the old scheme).
// T index in 16B units: (y<<9) + 16m + r; per-batch +16j folds into the
// load immediate; invalid y redirects into the 512 B zero pad.
// ---------------------------------------------------------------------------
__global__ __launch_bounds__(256) void epi_gather_f16(const uint4* __restrict__ Tq,
                                                      const float* __restrict__ x,
                                                      const float* __restrict__ F,
                                                      float* __restrict__ out) {
    int tid = blockIdx.x * 256 + threadIdx.x;
    int r   = tid & 15;          // lane-in-pixel, r = 2k + h
    int k   = r >> 1;            // sample phase: s ≡ k (mod 8)
    int h   = r & 1;             // channel half: ch 8h..8h+7
    int pix = tid >> 4;

    LineGeom g = make_geom(F, pix);
    f4 a0 = {0.f, 0.f, 0.f, 0.f};
    f4 a1 = {0.f, 0.f, 0.f, 0.f};

    if (g.col) {
        // exact per-sample chains for my 32 samples (s = 8m + k)
        int ych[32];
#pragma unroll
        for (int m = 0; m < 32; ++m) ych[m] = chainY(g, 8 * m + k);

        const int PADB = NPIX * 2;      // T size in 16B units (= 131072)
        int padr = PADB + r;            // zero-pad slot for this lane
        int rb   = r;                   // r + 128*b, incremented per batch

#pragma unroll
        for (int b = 0; b < 4; ++b) {
            int adr[8];
#pragma unroll
            for (int j = 0; j < 8; ++j) {
                int y  = ych[8 * b + j];
                int av = (int)((unsigned)y << 9) + rb;
                adr[j] = ((unsigned)y < 256u) ? av : (padr - 16 * j);
            }
            // batch-issue 8 independent 16B loads; +16j folds into imm offset
            uint4 v0 = Tq[adr[0] +   0];
            uint4 v1 = Tq[adr[1] +  16];
            uint4 v2 = Tq[adr[2] +  32];
            uint4 v3 = Tq[adr[3] +  48];
            uint4 v4 = Tq[adr[4] +  64];
            uint4 v5 = Tq[adr[5] +  80];
            uint4 v6 = Tq[adr[6] +  96];
            uint4 v7 = Tq[adr[7] + 112];
            acc16(v0, a0, a1); acc16(v1, a0, a1);
            acc16(v2, a0, a1); acc16(v3, a0, a1);
            acc16(v4, a0, a1); acc16(v5, a0, a1);
            acc16(v6, a0, a1); acc16(v7, a0, a1);
            rb += 128;
        }
    } else {
        // Row mode (never taken for this F; generic correctness): per-sample
        // scalar gathers from x (fp32) for this lane's channel half.
        int ch0 = h * 8;
        for (int m = 0; m < 32; ++m) {
            int s  = 8 * m + k;
            int xi = chainY(g, s);
            if ((unsigned)xi < 256u) {
                int addr = s * WSZ + xi;
                a0.x += x[(ch0 + 0) * NPIX + addr];
                a0.y += x[(ch0 + 1) * NPIX + addr];
                a0.z += x[(ch0 + 2) * NPIX + addr];
                a0.w += x[(ch0 + 3) * NPIX + addr];
                a1.x += x[(ch0 + 4) * NPIX + addr];
                a1.y += x[(ch0 + 5) * NPIX + addr];
                a1.z += x[(ch0 + 6) * NPIX + addr];
                a1.w += x[(ch0 + 7) * NPIX + addr];
            }
        }
    }

    // reduce over the 8 sample-slots (lane bits 1..3 within the 16-lane group)
#pragma unroll
    for (int d = 2; d <= 8; d <<= 1) {
        a0.x += __shfl_xor(a0.x, d, 64);
        a0.y += __shfl_xor(a0.y, d, 64);
        a0.z += __shfl_xor(a0.z, d, 64);
        a0.w += __shfl_xor(a0.w, d, 64);
        a1.x += __shfl_xor(a1.x, d, 64);
        a1.y += __shfl_xor(a1.y, d, 64);
        a1.z += __shfl_xor(a1.z, d, 64);
        a1.w += __shfl_xor(a1.w, d, 64);
    }

    if ((r & 14) == 0) {                 // lanes r=0 (ch 0-7) and r=1 (ch 8-15)
        int ch0 = h * 8;
        out[(ch0 + 0) * NPIX + pix] = a0.x;
        out[(ch0 + 1) * NPIX + pix] = a0.y;
        out[(ch0 + 2) * NPIX + pix] = a0.z;
        out[(ch0 + 3) * NPIX + pix] = a0.w;
        out[(ch0 + 4) * NPIX + pix] = a1.x;
        out[(ch0 + 5) * NPIX + pix] = a1.y;
        out[(ch0 + 6) * NPIX + pix] = a1.z;
        out[(ch0 + 7) * NPIX + pix] = a1.w;
    }
}

// ---------------------------------------------------------------------------
// Fallback without workspace: direct per-sample fp32 gathers from (bc,h,w).
// ---------------------------------------------------------------------------
__global__ __launch_bounds__(256) void epi_gather_direct(const float* __restrict__ x,
                                                         const float* __restrict__ F,
                                                         float* __restrict__ out) {
    int tid  = blockIdx.x * 256 + threadIdx.x;
    int quad = tid & 3;
    int pix  = tid >> 2;

    LineGeom g = make_geom(F, pix);

    float4 acc = make_float4(0.f, 0.f, 0.f, 0.f);
    int base = quad * 4;

#pragma unroll 2
    for (int s = 0; s < 256; ++s) {
        int  yi    = chainY(g, s);
        bool valid = ((unsigned)yi < 256u);
        int  tcl   = valid ? yi : 0;
        int  addr  = g.col ? (tcl * WSZ + s) : (s * WSZ + tcl);
        if (valid) {
            acc.x += x[(base + 0) * NPIX + addr];
            acc.y += x[(base + 1) * NPIX + addr];
            acc.z += x[(base + 2) * NPIX + addr];
            acc.w += x[(base + 3) * NPIX + addr];
        }
    }

    out[(base + 0) * NPIX + pix] = acc.x;
    out[(base + 1) * NPIX + pix] = acc.y;
    out[(base + 2) * NPIX + pix] = acc.z;
    out[(base + 3) * NPIX + pix] = acc.w;
}

extern "C" void kernel_launch(void* const* d_in, const int* in_sizes, int n_in,
                              void* d_out, int out_size, void* d_ws, size_t ws_size,
                              hipStream_t stream) {
    const float* x   = (const float*)d_in[0];
    const float* F   = (const float*)d_in[1];
    float*       out = (float*)d_out;

    const size_t need = (size_t)NELEM * sizeof(__half) + 512;
    if (ws_size >= need) {
        __half* T = (__half*)d_ws;
        transpose_f16<<<NPIX / 256, 256, 0, stream>>>(x, T);
        epi_gather_f16<<<(NPIX * 16) / 256, 256, 0, stream>>>((const uint4*)T, x, F, out);
    } else {
        epi_gather_direct<<<(NPIX * 4) / 256, 256, 0, stream>>>(x, F, out);
    }
}

// Round 3
// 80.609 us; speedup vs baseline: 1.1487x; 1.1487x over previous
//
#include <hip/hip_runtime.h>
#include <hip/hip_fp16.h>

// x: (2,8,256,256) fp32, F: 3x3 fp32.
#define HS 256
#define WSZ 256
#define NPIX (HS * WSZ)        // 65536 pixels
#define NCH 16                 // B*C
#define NELEM (NPIX * NCH)     // half elements in T

typedef float f4 __attribute__((ext_vector_type(4)));

// ---------------------------------------------------------------------------
// Transpose + fp16 quantize: (bc, h, w) f32 -> (h, w, bc) f16, LDS-tiled,
// coalesced both sides. Geometry/rint decisions are unaffected (they use F
// in fp32); only sampled VALUES are RTN-quantized once here.
// Also zeroes a 512 B pad at T[NELEM..) — the invalid-sample redirect target.
// ---------------------------------------------------------------------------
__global__ __launch_bounds__(256) void transpose_f16(const float* __restrict__ x,
                                                     __half* __restrict__ T) {
    __shared__ float lds[16][257];   // +1 pad
    int tid  = threadIdx.x;
    int base = blockIdx.x * 256;
#pragma unroll
    for (int ch = 0; ch < 16; ++ch)
        lds[ch][tid] = x[ch * NPIX + base + tid];   // coalesced 1KB per instr
    if (blockIdx.x == 0 && tid < 128)
        ((unsigned int*)(T + NELEM))[tid] = 0u;     // 512 B zero pad
    __syncthreads();
    uint2* T2 = (uint2*)T;           // 8 B = 4 halves = one channel-quad
#pragma unroll
    for (int it = 0; it < 4; ++it) {
        int idx = it * 256 + tid;    // 0..1023 uint2 of this tile
        int p   = idx >> 2;          // local pixel
        int q   = idx & 3;           // channel quad
        __half2 a = __floats2half2_rn(lds[q * 4 + 0][p], lds[q * 4 + 1][p]);
        __half2 b = __floats2half2_rn(lds[q * 4 + 2][p], lds[q * 4 + 3][p]);
        uint2 o;
        o.x = __builtin_bit_cast(unsigned int, a);
        o.y = __builtin_bit_cast(unsigned int, b);
        T2[base * 4 + idx] = o;      // contiguous 8B/lane -> coalesced
    }
}

// ---------------------------------------------------------------------------
// Geometry (bit-exact, verified R6): FMA-contracted einsum, f32. UNCHANGED.
// ---------------------------------------------------------------------------
struct LineGeom {
    float p, q, c;
    bool  col;
};

__device__ __forceinline__ LineGeom make_geom(const float* __restrict__ F, int pix) {
#pragma clang fp contract(off)
    int w = pix & (WSZ - 1);
    int h = pix >> 8;
    float u = (float)w, v = (float)h;
    float a = __builtin_fmaf(F[3], v, F[0] * u) + F[6];
    float b = __builtin_fmaf(F[4], v, F[1] * u) + F[7];
    float c = __builtin_fmaf(F[5], v, F[2] * u) + F[8];
    const float eps = 1e-8f;
    float bs = (fabsf(b) < eps) ? eps : b;
    float as = (fabsf(a) < eps) ? eps : a;
    LineGeom g;
    g.col = (fabsf(b) >= fabsf(a));
    g.p   = g.col ? a : b;
    g.q   = g.col ? bs : as;
    g.c   = c;
    return g;
}

// Chain (bit-exact, verified R6): t = fma(p,s,c); y = (-t)/q IEEE f32; rint.
// MUST stay a true IEEE divide per sample: rcp-based y flips rint at half-
// integer boundaries and blows the tolerance. Each chain is now computed by
// exactly ONE lane and DPP-shared to its pair lane (bit-exact int move).
__device__ __forceinline__ int chainY(const LineGeom& g, int s) {
#pragma clang fp contract(off)
    float t  = __builtin_fmaf(g.p, (float)s, g.c);
    float y  = (-t) / g.q;
    return (int)__builtin_rintf(y);
}

__device__ __forceinline__ __half2 bch2(unsigned int v) {
    return __builtin_bit_cast(__half2, v);
}

// ---------------------------------------------------------------------------
// Gather v4: same mapping/memory shape as v3 (verified): 16 lanes/pixel =
// 8 sample-slots x 2 channel-halves; lane r=2k+h loads 16 B (8 ch, half h)
// of sample s = 8m+k; a pixel's 16 lanes cover 8 consecutive samples =
// 256 B contiguous per load instruction. VALU cuts vs v3:
//  (a) chains computed ONCE per lane-pair: lane computes jj = 4h+i of each
//      batch, quad_perm(1,0,3,2) DPP swap delivers the partner's 4
//      (divides/thread 32 -> 16; bit-exact, int move);
//  (b) fp16 partial accumulation: 4x v_pk_add_f16 per load into batch-local
//      partials (8 samples max -> |sum|<~11, fp16 eps 0.008 -> error <~0.03),
//      converted to f32 once per batch.
// T index in 16B units: (y<<9) + r + 128b + 16j (16j folds into load imm);
// invalid y redirects into the 512 B zero pad (compensated for the imm).
// ---------------------------------------------------------------------------
#define QUAD_BCAST(dst, src, ctrl)                                              \
    dst = __builtin_amdgcn_mov_dpp(src, ctrl, 0xf, 0xf, false)

__global__ __launch_bounds__(256) void epi_gather_f16(const uint4* __restrict__ Tq,
                                                      const float* __restrict__ x,
                                                      const float* __restrict__ F,
                                                      float* __restrict__ out) {
    int tid = blockIdx.x * 256 + threadIdx.x;
    int r   = tid & 15;          // lane-in-pixel, r = 2k + h
    int k   = r >> 1;            // sample phase: s ≡ k (mod 8)
    int h   = r & 1;             // channel half: ch 8h..8h+7
    int pix = tid >> 4;

    LineGeom g = make_geom(F, pix);
    f4 a0 = {0.f, 0.f, 0.f, 0.f};
    f4 a1 = {0.f, 0.f, 0.f, 0.f};

    if (g.col) {
        const int PADB = NPIX * 2;      // T size in 16B units (= 131072)
        int  padr = PADB + r;           // zero-pad slot for this lane
        int  rb   = r;                  // r + 128*b, incremented per batch
        bool hb   = (h != 0);
        int  sb   = (h << 5) + k;       // own chains: s = sb + 64b + 8i

#pragma unroll
        for (int b = 0; b < 4; ++b) {
            // (a) 4 own chains (jj = 4h+i), then swap with pair lane
            int yown[4], yswp[4];
#pragma unroll
            for (int i = 0; i < 4; ++i) yown[i] = chainY(g, sb + 64 * b + 8 * i);
#pragma unroll
            for (int i = 0; i < 4; ++i) QUAD_BCAST(yswp[i], yown[i], 0xB1);

            int adr[8];
#pragma unroll
            for (int i = 0; i < 4; ++i) {
                int ylo = hb ? yswp[i] : yown[i];   // chain of j = i
                int yhi = hb ? yown[i] : yswp[i];   // chain of j = i+4
                int alo = (int)((unsigned)ylo << 9) + rb;
                int ahi = (int)((unsigned)yhi << 9) + rb;
                adr[i]     = ((unsigned)ylo < 256u) ? alo : (padr - 16 * i);
                adr[i + 4] = ((unsigned)yhi < 256u) ? ahi : (padr - 16 * (i + 4));
            }
            // batch-issue 8 independent 16B loads; +16j folds into imm offset
            uint4 v0 = Tq[adr[0] +   0];
            uint4 v1 = Tq[adr[1] +  16];
            uint4 v2 = Tq[adr[2] +  32];
            uint4 v3 = Tq[adr[3] +  48];
            uint4 v4 = Tq[adr[4] +  64];
            uint4 v5 = Tq[adr[5] +  80];
            uint4 v6 = Tq[adr[6] +  96];
            uint4 v7 = Tq[adr[7] + 112];

            // (b) fp16 batch partials: 4 pk_add_f16 per load
            __half2 zz = __floats2half2_rn(0.f, 0.f);
            __half2 s0 = zz, s1 = zz, s2 = zz, s3 = zz;
#define ACC(V)                                                                  \
            s0 = __hadd2(s0, bch2((V).x));                                      \
            s1 = __hadd2(s1, bch2((V).y));                                      \
            s2 = __hadd2(s2, bch2((V).z));                                      \
            s3 = __hadd2(s3, bch2((V).w));
            ACC(v0) ACC(v1) ACC(v2) ACC(v3) ACC(v4) ACC(v5) ACC(v6) ACC(v7)
#undef ACC
            float2 f;
            f = __half22float2(s0); a0.x += f.x; a0.y += f.y;
            f = __half22float2(s1); a0.z += f.x; a0.w += f.y;
            f = __half22float2(s2); a1.x += f.x; a1.y += f.y;
            f = __half22float2(s3); a1.z += f.x; a1.w += f.y;

            rb += 128;
        }
    } else {
        // Row mode (never taken for this F; generic correctness): per-sample
        // scalar gathers from x (fp32) for this lane's channel half.
        int ch0 = h * 8;
        for (int m = 0; m < 32; ++m) {
            int s  = 8 * m + k;
            int xi = chainY(g, s);
            if ((unsigned)xi < 256u) {
                int addr = s * WSZ + xi;
                a0.x += x[(ch0 + 0) * NPIX + addr];
                a0.y += x[(ch0 + 1) * NPIX + addr];
                a0.z += x[(ch0 + 2) * NPIX + addr];
                a0.w += x[(ch0 + 3) * NPIX + addr];
                a1.x += x[(ch0 + 4) * NPIX + addr];
                a1.y += x[(ch0 + 5) * NPIX + addr];
                a1.z += x[(ch0 + 6) * NPIX + addr];
                a1.w += x[(ch0 + 7) * NPIX + addr];
            }
        }
    }

    // reduce over the 8 sample-slots (lane bits 1..3 within the 16-lane group)
#pragma unroll
    for (int d = 2; d <= 8; d <<= 1) {
        a0.x += __shfl_xor(a0.x, d, 64);
        a0.y += __shfl_xor(a0.y, d, 64);
        a0.z += __shfl_xor(a0.z, d, 64);
        a0.w += __shfl_xor(a0.w, d, 64);
        a1.x += __shfl_xor(a1.x, d, 64);
        a1.y += __shfl_xor(a1.y, d, 64);
        a1.z += __shfl_xor(a1.z, d, 64);
        a1.w += __shfl_xor(a1.w, d, 64);
    }

    if ((r & 14) == 0) {                 // lanes r=0 (ch 0-7) and r=1 (ch 8-15)
        int ch0 = h * 8;
        out[(ch0 + 0) * NPIX + pix] = a0.x;
        out[(ch0 + 1) * NPIX + pix] = a0.y;
        out[(ch0 + 2) * NPIX + pix] = a0.z;
        out[(ch0 + 3) * NPIX + pix] = a0.w;
        out[(ch0 + 4) * NPIX + pix] = a1.x;
        out[(ch0 + 5) * NPIX + pix] = a1.y;
        out[(ch0 + 6) * NPIX + pix] = a1.z;
        out[(ch0 + 7) * NPIX + pix] = a1.w;
    }
}

// ---------------------------------------------------------------------------
// Fallback without workspace: direct per-sample fp32 gathers from (bc,h,w).
// ---------------------------------------------------------------------------
__global__ __launch_bounds__(256) void epi_gather_direct(const float* __restrict__ x,
                                                         const float* __restrict__ F,
                                                         float* __restrict__ out) {
    int tid  = blockIdx.x * 256 + threadIdx.x;
    int quad = tid & 3;
    int pix  = tid >> 2;

    LineGeom g = make_geom(F, pix);

    float4 acc = make_float4(0.f, 0.f, 0.f, 0.f);
    int base = quad * 4;

#pragma unroll 2
    for (int s = 0; s < 256; ++s) {
        int  yi    = chainY(g, s);
        bool valid = ((unsigned)yi < 256u);
        int  tcl   = valid ? yi : 0;
        int  addr  = g.col ? (tcl * WSZ + s) : (s * WSZ + tcl);
        if (valid) {
            acc.x += x[(base + 0) * NPIX + addr];
            acc.y += x[(base + 1) * NPIX + addr];
            acc.z += x[(base + 2) * NPIX + addr];
            acc.w += x[(base + 3) * NPIX + addr];
        }
    }

    out[(base + 0) * NPIX + pix] = acc.x;
    out[(base + 1) * NPIX + pix] = acc.y;
    out[(base + 2) * NPIX + pix] = acc.z;
    out[(base + 3) * NPIX + pix] = acc.w;
}

extern "C" void kernel_launch(void* const* d_in, const int* in_sizes, int n_in,
                              void* d_out, int out_size, void* d_ws, size_t ws_size,
                              hipStream_t stream) {
    const float* x   = (const float*)d_in[0];
    const float* F   = (const float*)d_in[1];
    float*       out = (float*)d_out;

    const size_t need = (size_t)NELEM * sizeof(__half) + 512;
    if (ws_size >= need) {
        __half* T = (__half*)d_ws;
        transpose_f16<<<NPIX / 256, 256, 0, stream>>>(x, T);
        epi_gather_f16<<<(NPIX * 16) / 256, 256, 0, stream>>>((const uint4*)T, x, F, out);
    } else {
        epi_gather_direct<<<(NPIX * 4) / 256, 256, 0, stream>>>(x, F, out);
    }
}

// Round 5
// 80.131 us; speedup vs baseline: 1.1555x; 1.0060x over previous
//
#include <hip/hip_runtime.h>
#include <hip/hip_fp16.h>

// x: (2,8,256,256) fp32, F: 3x3 fp32.
#define HS 256
#define WSZ 256
#define NPIX (HS * WSZ)        // 65536 pixels
#define NCH 16                 // B*C
#define NELEM (NPIX * NCH)     // half elements in T

typedef float f4 __attribute__((ext_vector_type(4)));

// ---------------------------------------------------------------------------
// Transpose + fp16 quantize: (bc, h, w) f32 -> (h, w, bc) f16, LDS-tiled,
// coalesced both sides. Geometry/rint decisions are unaffected (f32 from F);
// only sampled VALUES are RTN-quantized once here.
// Also zeroes a 512 B pad at T[NELEM..) — the invalid-sample redirect target.
// ---------------------------------------------------------------------------
__global__ __launch_bounds__(256) void transpose_f16(const float* __restrict__ x,
                                                     __half* __restrict__ T) {
    __shared__ float lds[16][257];   // +1 pad
    int tid  = threadIdx.x;
    int base = blockIdx.x * 256;
#pragma unroll
    for (int ch = 0; ch < 16; ++ch)
        lds[ch][tid] = x[ch * NPIX + base + tid];   // coalesced 1KB per instr
    if (blockIdx.x == 0 && tid < 128)
        ((unsigned int*)(T + NELEM))[tid] = 0u;     // 512 B zero pad
    __syncthreads();
    uint2* T2 = (uint2*)T;           // 8 B = 4 halves = one channel-quad
#pragma unroll
    for (int it = 0; it < 4; ++it) {
        int idx = it * 256 + tid;    // 0..1023 uint2 of this tile
        int p   = idx >> 2;          // local pixel
        int q   = idx & 3;           // channel quad
        __half2 a = __floats2half2_rn(lds[q * 4 + 0][p], lds[q * 4 + 1][p]);
        __half2 b = __floats2half2_rn(lds[q * 4 + 2][p], lds[q * 4 + 3][p]);
        uint2 o;
        o.x = __builtin_bit_cast(unsigned int, a);
        o.y = __builtin_bit_cast(unsigned int, b);
        T2[base * 4 + idx] = o;      // contiguous 8B/lane -> coalesced
    }
}

// ---------------------------------------------------------------------------
// Geometry (bit-exact, verified R6): FMA-contracted einsum, f32. UNCHANGED.
// ---------------------------------------------------------------------------
struct LineGeom {
    float p, q, c;
    bool  col;
};

__device__ __forceinline__ LineGeom make_geom(const float* __restrict__ F, int pix) {
#pragma clang fp contract(off)
    int w = pix & (WSZ - 1);
    int h = pix >> 8;
    float u = (float)w, v = (float)h;
    float a = __builtin_fmaf(F[3], v, F[0] * u) + F[6];
    float b = __builtin_fmaf(F[4], v, F[1] * u) + F[7];
    float c = __builtin_fmaf(F[5], v, F[2] * u) + F[8];
    const float eps = 1e-8f;
    float bs = (fabsf(b) < eps) ? eps : b;
    float as = (fabsf(a) < eps) ? eps : a;
    LineGeom g;
    g.col = (fabsf(b) >= fabsf(a));
    g.p   = g.col ? a : b;
    g.q   = g.col ? bs : as;
    g.c   = c;
    return g;
}

// Exact chain (reference-bit-exact): t = fma(p,s,c); y = (-t)/q IEEE; rint.
// Used by row-mode and the direct fallback kernel.
__device__ __forceinline__ int chainY(const LineGeom& g, int s) {
#pragma clang fp contract(off)
    float t  = __builtin_fmaf(g.p, (float)s, g.c);
    float y  = (-t) / g.q;
    return (int)__builtin_rintf(y);
}

// Fast chain: rcp + 1 Newton + Markstein. |y1 - IEEE_div| <= ~1.5 ulp
// (<= 4.6e-5 for |y| < 512). A rint flip vs the exact chain requires y
// within that of a half-integer; detector |frac-0.5| < 2e-4 (4x margin)
// redirects those rare lanes (~4e-4/sample) to the true IEEE divide.
// => rint result is bit-identical to chainY for ALL samples.
__device__ __forceinline__ int chainY_fast(const LineGeom& g, float rq, int s) {
#pragma clang fp contract(off)
    float num = __builtin_fmaf(-g.p, (float)s, -g.c);   // == -fma(p,s,c) exactly
    float y0  = num * rq;
    float e   = __builtin_fmaf(-g.q, y0, num);
    float y1  = __builtin_fmaf(e, rq, y0);
    float fr  = y1 - floorf(y1);
    if (__builtin_expect(fabsf(fr - 0.5f) < 2e-4f, 0))
        y1 = num / g.q;                                  // exact IEEE fallback
    return (int)__builtin_rintf(y1);
}

__device__ __forceinline__ __half2 bch2(unsigned int v) {
    return __builtin_bit_cast(__half2, v);
}

// DPP rotate-add within the 16-lane row (no LDS, no lgkm waits).
// CTRL must be a compile-time constant (builtin requirement) -> template.
template <int CTRL>
__device__ __forceinline__ float dpp_ror_add(float v) {
    int t = __builtin_amdgcn_mov_dpp(__builtin_bit_cast(int, v), CTRL, 0xf, 0xf, true);
    return v + __builtin_bit_cast(float, t);
}

template <int CTRL>
__device__ __forceinline__ void ror_add8(f4& a0, f4& a1) {
    a0.x = dpp_ror_add<CTRL>(a0.x);
    a0.y = dpp_ror_add<CTRL>(a0.y);
    a0.z = dpp_ror_add<CTRL>(a0.z);
    a0.w = dpp_ror_add<CTRL>(a0.w);
    a1.x = dpp_ror_add<CTRL>(a1.x);
    a1.y = dpp_ror_add<CTRL>(a1.y);
    a1.z = dpp_ror_add<CTRL>(a1.z);
    a1.w = dpp_ror_add<CTRL>(a1.w);
}

// ---------------------------------------------------------------------------
// Gather v5 (v4 memory shape, VALU-trimmed): 16 lanes/pixel = 8 sample-slots
// x 2 channel-halves; lane r=2k+h loads 16 B (8 ch, half h) of s = 8m+k; a
// pixel's 16 lanes cover 8 consecutive samples = 256 B contiguous per load.
// Cuts vs v4:
//  (a) divides via chainY_fast (rcp+NR+Markstein + exact-fallback detector;
//      rint bit-identical) — ~14 -> ~10 instr/chain, 16 chains/lane;
//  (b) f16 partials held across 2 batches (batch-end conversions halved);
//  (c) slot-reduce via DPP row_ror fused adds (wait-free) instead of shfl.
// ---------------------------------------------------------------------------
#define QUAD_BCAST(dst, src, ctrl)                                              \
    dst = __builtin_amdgcn_mov_dpp(src, ctrl, 0xf, 0xf, false)

__global__ __launch_bounds__(256) void epi_gather_f16(const uint4* __restrict__ Tq,
                                                      const float* __restrict__ x,
                                                      const float* __restrict__ F,
                                                      float* __restrict__ out) {
    int tid = blockIdx.x * 256 + threadIdx.x;
    int r   = tid & 15;          // lane-in-pixel, r = 2k + h
    int k   = r >> 1;            // sample phase: s ≡ k (mod 8)
    int h   = r & 1;             // channel half: ch 8h..8h+7
    int pix = tid >> 4;

    LineGeom g = make_geom(F, pix);
    f4 a0 = {0.f, 0.f, 0.f, 0.f};
    f4 a1 = {0.f, 0.f, 0.f, 0.f};

    if (g.col) {
        // per-pixel reciprocal for the fast chain (1 rcp + 1 NR step)
        float r0 = __builtin_amdgcn_rcpf(g.q);
        float rq = __builtin_fmaf(__builtin_fmaf(-g.q, r0, 1.0f), r0, r0);

        const int PADB = NPIX * 2;      // T size in 16B units (= 131072)
        int  padr = PADB + r;           // zero-pad slot for this lane
        int  rb   = r;                  // r + 128*b, incremented per batch
        bool hb   = (h != 0);
        int  sb   = (h << 5) + k;       // own chains: s = sb + 64b + 8i

#pragma unroll
        for (int bb = 0; bb < 2; ++bb) {
            // f16 partials live across TWO batches (16 samples max per slot)
            __half2 zz = __floats2half2_rn(0.f, 0.f);
            __half2 s0 = zz, s1 = zz, s2 = zz, s3 = zz;

#pragma unroll
            for (int b2 = 0; b2 < 2; ++b2) {
                int b = 2 * bb + b2;
                // 4 own chains (jj = 4h+i), then swap with pair lane
                int yown[4], yswp[4];
#pragma unroll
                for (int i = 0; i < 4; ++i)
                    yown[i] = chainY_fast(g, rq, sb + 64 * b + 8 * i);
#pragma unroll
                for (int i = 0; i < 4; ++i) QUAD_BCAST(yswp[i], yown[i], 0xB1);

                int adr[8];
#pragma unroll
                for (int i = 0; i < 4; ++i) {
                    int ylo = hb ? yswp[i] : yown[i];   // chain of j = i
                    int yhi = hb ? yown[i] : yswp[i];   // chain of j = i+4
                    int alo = (int)((unsigned)ylo << 9) + rb;
                    int ahi = (int)((unsigned)yhi << 9) + rb;
                    adr[i]     = ((unsigned)ylo < 256u) ? alo : (padr - 16 * i);
                    adr[i + 4] = ((unsigned)yhi < 256u) ? ahi : (padr - 16 * (i + 4));
                }
                // batch-issue 8 independent 16B loads; +16j folds into imm
                uint4 v0 = Tq[adr[0] +   0];
                uint4 v1 = Tq[adr[1] +  16];
                uint4 v2 = Tq[adr[2] +  32];
                uint4 v3 = Tq[adr[3] +  48];
                uint4 v4 = Tq[adr[4] +  64];
                uint4 v5 = Tq[adr[5] +  80];
                uint4 v6 = Tq[adr[6] +  96];
                uint4 v7 = Tq[adr[7] + 112];

#define ACC(V)                                                                  \
                s0 = __hadd2(s0, bch2((V).x));                                  \
                s1 = __hadd2(s1, bch2((V).y));                                  \
                s2 = __hadd2(s2, bch2((V).z));                                  \
                s3 = __hadd2(s3, bch2((V).w));
                ACC(v0) ACC(v1) ACC(v2) ACC(v3) ACC(v4) ACC(v5) ACC(v6) ACC(v7)
#undef ACC
                rb += 128;
            }
            // fold the 2-batch f16 partials into f32 accumulators
            float2 f;
            f = __half22float2(s0); a0.x += f.x; a0.y += f.y;
            f = __half22float2(s1); a0.z += f.x; a0.w += f.y;
            f = __half22float2(s2); a1.x += f.x; a1.y += f.y;
            f = __half22float2(s3); a1.z += f.x; a1.w += f.y;
        }
    } else {
        // Row mode (never taken for this F; generic correctness): per-sample
        // scalar gathers from x (fp32) for this lane's channel half.
        int ch0 = h * 8;
        for (int m = 0; m < 32; ++m) {
            int s  = 8 * m + k;
            int xi = chainY(g, s);
            if ((unsigned)xi < 256u) {
                int addr = s * WSZ + xi;
                a0.x += x[(ch0 + 0) * NPIX + addr];
                a0.y += x[(ch0 + 1) * NPIX + addr];
                a0.z += x[(ch0 + 2) * NPIX + addr];
                a0.w += x[(ch0 + 3) * NPIX + addr];
                a1.x += x[(ch0 + 4) * NPIX + addr];
                a1.y += x[(ch0 + 5) * NPIX + addr];
                a1.z += x[(ch0 + 6) * NPIX + addr];
                a1.w += x[(ch0 + 7) * NPIX + addr];
            }
        }
    }

    // reduce over the 8 sample-slots: DPP row_ror 8,4,2 (preserves lane bit0,
    // sums all 8 same-parity slots; wait-free VALU, no LDS)
    ror_add8<0x128>(a0, a1);   // row_ror:8
    ror_add8<0x124>(a0, a1);   // row_ror:4
    ror_add8<0x122>(a0, a1);   // row_ror:2

    if ((r & 14) == 0) {                 // lanes r=0 (ch 0-7) and r=1 (ch 8-15)
        int ch0 = h * 8;
        out[(ch0 + 0) * NPIX + pix] = a0.x;
        out[(ch0 + 1) * NPIX + pix] = a0.y;
        out[(ch0 + 2) * NPIX + pix] = a0.z;
        out[(ch0 + 3) * NPIX + pix] = a0.w;
        out[(ch0 + 4) * NPIX + pix] = a1.x;
        out[(ch0 + 5) * NPIX + pix] = a1.y;
        out[(ch0 + 6) * NPIX + pix] = a1.z;
        out[(ch0 + 7) * NPIX + pix] = a1.w;
    }
}

// ---------------------------------------------------------------------------
// Fallback without workspace: direct per-sample fp32 gathers from (bc,h,w).
// ---------------------------------------------------------------------------
__global__ __launch_bounds__(256) void epi_gather_direct(const float* __restrict__ x,
                                                         const float* __restrict__ F,
                                                         float* __restrict__ out) {
    int tid  = blockIdx.x * 256 + threadIdx.x;
    int quad = tid & 3;
    int pix  = tid >> 2;

    LineGeom g = make_geom(F, pix);

    float4 acc = make_float4(0.f, 0.f, 0.f, 0.f);
    int base = quad * 4;

#pragma unroll 2
    for (int s = 0; s < 256; ++s) {
        int  yi    = chainY(g, s);
        bool valid = ((unsigned)yi < 256u);
        int  tcl   = valid ? yi : 0;
        int  addr  = g.col ? (tcl * WSZ + s) : (s * WSZ + tcl);
        if (valid) {
            acc.x += x[(base + 0) * NPIX + addr];
            acc.y += x[(base + 1) * NPIX + addr];
            acc.z += x[(base + 2) * NPIX + addr];
            acc.w += x[(base + 3) * NPIX + addr];
        }
    }

    out[(base + 0) * NPIX + pix] = acc.x;
    out[(base + 1) * NPIX + pix] = acc.y;
    out[(base + 2) * NPIX + pix] = acc.z;
    out[(base + 3) * NPIX + pix] = acc.w;
}

extern "C" void kernel_launch(void* const* d_in, const int* in_sizes, int n_in,
                              void* d_out, int out_size, void* d_ws, size_t ws_size,
                              hipStream_t stream) {
    const float* x   = (const float*)d_in[0];
    const float* F   = (const float*)d_in[1];
    float*       out = (float*)d_out;

    const size_t need = (size_t)NELEM * sizeof(__half) + 512;
    if (ws_size >= need) {
        __half* T = (__half*)d_ws;
        transpose_f16<<<NPIX / 256, 256, 0, stream>>>(x, T);
        epi_gather_f16<<<(NPIX * 16) / 256, 256, 0, stream>>>((const uint4*)T, x, F, out);
    } else {
        epi_gather_direct<<<(NPIX * 4) / 256, 256, 0, stream>>>(x, F, out);
    }
}